// Round 1
// baseline (340.601 us; speedup 1.0000x reference)
//
#include <hip/hip_runtime.h>
#include <cstddef>

// ============================================================================
// VLSTM via bf16 MFMA, R5: single-barrier steady state.
//  - Occupancy analysis: ~192 unified regs/wave -> 2 waves/SIMD (8 waves/CU),
//    so regs up to 256 are FREE. Spend them on: h carried in registers,
//    x/mask prefetch, double-buffered A.
//  - A[2]: GEMM(t) reads A[t&1]; h(t) (merged, written unconditionally from
//    h-regs) + emb(t+1) go to A[(t+1)&1]. No intra-step RAW hazard ->
//    ONE __syncthreads() per step (was 2).
//  - x(t+1)/mask(t+1) issued at loop top, consumed after activations
//    (issue-early / write-late): HBM latency hidden under GEMM+activations.
//  - out-proj mask comes from in-register mbits (no LDS mask re-read).
//  - bf16 converts via __bf16 cast (v_cvt_pk_bf16_f32), RNE == old f2bf.
// ============================================================================

typedef __attribute__((ext_vector_type(8))) short  s16x8;   // 8 x bf16
typedef __attribute__((ext_vector_type(4))) float  f32x4;

namespace {
constexpr int T_STEPS = 20;
constexpr int NN      = 32768;
constexpr int D_EMB   = 64;
constexpr int D_H     = 128;
constexpr int D_OUT   = 5;
constexpr int G4      = 512;
constexpr int MT      = 64;
constexpr int BLOCK   = 512;
constexpr int GRID    = NN / MT;
constexpr int WP_ELEMS   = 8 * 4 * 6 * 64 * 8;
constexpr int WOUT_ELEMS = 4 * 64 * 8;
constexpr int A_ELEMS    = 24 * 64 * 8;
constexpr size_t OFF_H = (size_t)T_STEPS * NN * D_OUT;
constexpr size_t OFF_C = OFF_H + (size_t)NN * D_H;
}

__device__ __forceinline__ unsigned short f2bf(float x) {
    unsigned u = __float_as_uint(x);
    u = (u + 0x7FFFu + ((u >> 16) & 1u)) >> 16;     // RNE
    return (unsigned short)u;
}
__device__ __forceinline__ unsigned short f2bf_hw(float x) {
    __bf16 b = (__bf16)x;                            // RNE, hw cvt on gfx950
    union { __bf16 b; unsigned short u; } cv;
    cv.b = b;
    return cv.u;
}
__device__ __forceinline__ float bf2f(unsigned short h) {
    return __uint_as_float(((unsigned)h) << 16);
}
__device__ __forceinline__ float sigf(float x) {
    return __builtin_amdgcn_rcpf(1.0f + __expf(-x));
}
__device__ __forceinline__ float tanhf_fast(float x) {
    return fmaf(-2.0f, __builtin_amdgcn_rcpf(1.0f + __expf(2.0f * x)), 1.0f);
}

// ----------------------------------------------------------------------------
__global__ void prepack_kernel(const float* __restrict__ W_ih,
                               const float* __restrict__ b_ih,
                               const float* __restrict__ W_hh,
                               const float* __restrict__ b_hh,
                               const float* __restrict__ W_out,
                               unsigned short* __restrict__ Wp,
                               unsigned short* __restrict__ WoutF,
                               float* __restrict__ b_sum) {
    int idx = blockIdx.x * blockDim.x + threadIdx.x;
    if (idx < WP_ELEMS) {
        int j    = idx & 7;
        int L    = (idx >> 3) & 63;
        int rest = idx >> 9;
        int kb   = rest % 6;
        int gw   = rest / 6;
        int g    = gw & 3, w = gw >> 2;
        int k    = kb * 32 + (L >> 4) * 8 + j;
        int col  = g * D_H + w * 16 + (L & 15);
        float v  = (k < D_EMB) ? W_ih[k * G4 + col] : W_hh[(k - D_EMB) * G4 + col];
        Wp[idx] = f2bf(v);
    } else if (idx < WP_ELEMS + WOUT_ELEMS) {
        int i2 = idx - WP_ELEMS;
        int j = i2 & 7, L = (i2 >> 3) & 63, kb2 = i2 >> 9;
        int k = kb2 * 32 + (L >> 4) * 8 + j;
        int n = L & 15;
        WoutF[i2] = (n < D_OUT) ? f2bf(W_out[k * D_OUT + n]) : (unsigned short)0;
    }
    if (idx < G4) b_sum[idx] = b_ih[idx] + b_hh[idx];
}

// ----------------------------------------------------------------------------
__global__ __launch_bounds__(BLOCK, 2) void vlstm_kernel(
    const float* __restrict__ nodes,   // [T][N][2]
    const int*   __restrict__ mask,    // [T][N]
    const float* __restrict__ h0,      // [N][128]
    const float* __restrict__ c0,      // [N][128]
    const float* __restrict__ W_embed, // [2][64]
    const float* __restrict__ b_embed, // [64]
    const float* __restrict__ b_out,   // [5]
    const unsigned short* __restrict__ Wp,
    const unsigned short* __restrict__ WoutF,
    const float* __restrict__ b_sum,
    float* __restrict__ out)
{
    __shared__ __align__(16) unsigned short A[2][A_ELEMS];     // 48 KB dbuf
    __shared__ __align__(16) float st_out[2][MT * D_OUT];      // 2.5 KB dbuf
    __shared__ float We_s[2 * D_EMB];
    __shared__ float be_s[D_EMB];
    __shared__ int   msk_s[2][MT];

    const int tid  = threadIdx.x;
    const int wave = tid >> 6;
    const int L    = tid & 63;
    const int quad = L >> 4;
    const int l15  = L & 15;
    const int n_base = blockIdx.x * MT;

    // ---- weights -> registers, once ----
    const unsigned short* wbase = Wp + (size_t)wave * (4 * 6 * 64 * 8);
    s16x8 Bf[4][6];
    #pragma unroll
    for (int g = 0; g < 4; g++)
        #pragma unroll
        for (int kb = 0; kb < 6; kb++)
            Bf[g][kb] = *(const s16x8*)(wbase + ((g * 6 + kb) * 64 + L) * 8);
    s16x8 WoF[4];
    #pragma unroll
    for (int kb2 = 0; kb2 < 4; kb2++)
        WoF[kb2] = *(const s16x8*)(WoutF + ((kb2 * 64) + L) * 8);

    const int u_lane = wave * 16 + l15;
    float bias[4];
    #pragma unroll
    for (int g = 0; g < 4; g++) bias[g] = b_sum[g * D_H + wave * 16 + l15];
    const float bo = (l15 < D_OUT) ? b_out[l15] : 0.0f;

    // per-thread A-write geometry (h rows)
    const int kb_u = 2 + (u_lane >> 5);
    const int fl   = ((u_lane >> 3) & 3) * 16 + quad * 4;
    const int j_u  = u_lane & 7;

    // ---- one-time LDS staging ----
    for (int i = tid; i < 3 * D_EMB; i += BLOCK) {
        if (i < 2 * D_EMB) We_s[i] = W_embed[i];
        else               be_s[i - 2 * D_EMB] = b_embed[i - 2 * D_EMB];
    }

    // ---- h, c -> registers; h -> A[0] h-rows ----
    float          c[4][4];
    unsigned short hr[4][4];
    #pragma unroll
    for (int rt = 0; rt < 4; rt++)
        #pragma unroll
        for (int r = 0; r < 4; r++) {
            int m = rt * 16 + quad * 4 + r;
            c[rt][r]  = c0[(size_t)(n_base + m) * D_H + u_lane];
            hr[rt][r] = f2bf_hw(h0[(size_t)(n_base + m) * D_H + u_lane]);
            A[0][((rt * 6 + kb_u) * 64 + fl + r) * 8 + j_u] = hr[rt][r];
        }

    // ---- emb(0) + mask(0) -> A[0] ----
    const int node_e = tid >> 3;
    const int eb     = tid & 7;
    const int idx_e  = (((node_e >> 4) * 6 + (eb >> 2)) * 64 + (eb & 3) * 16 + (node_e & 15)) * 8;
    {
        const float2* xp = (const float2*)(nodes + ((size_t)0 * NN + n_base + node_e) * 2);
        float2 x = *xp;
        s16x8 ev;
        #pragma unroll
        for (int j = 0; j < 8; j++) {
            int e = eb * 8 + j;
            float v = fmaf(x.x, We_s[e], fmaf(x.y, We_s[D_EMB + e], be_s[e]));
            ev[j] = (short)f2bf_hw(fmaxf(v, 0.0f));
        }
        *(s16x8*)(&A[0][idx_e]) = ev;
        if (tid < MT) msk_s[0][tid] = mask[(size_t)0 * NN + n_base + tid];
    }
    __syncthreads();   // prologue barrier: A[0], msk_s[0] ready

    for (int t = 0; t < T_STEPS; t++) {
        unsigned short* __restrict__ Ar = A[t & 1];
        unsigned short* __restrict__ Aw = A[(t + 1) & 1];

        // ---- prefetch x(t+1), mask(t+1) (issue early, consume late) ----
        float2 xv = make_float2(0.0f, 0.0f);
        int    lm = 0;
        if (t + 1 < T_STEPS) {
            xv = *(const float2*)(nodes + ((size_t)(t + 1) * NN + n_base + node_e) * 2);
            if (tid < MT) lm = mask[(size_t)(t + 1) * NN + n_base + tid];
        }

        // ---- gate GEMM from Ar: 24 ds_read_b128 + 96 MFMA/wave ----
        f32x4 acc[4][4];
        #pragma unroll
        for (int rt = 0; rt < 4; rt++)
            #pragma unroll
            for (int g = 0; g < 4; g++)
                acc[rt][g] = (f32x4){bias[g], bias[g], bias[g], bias[g]};
        #pragma unroll
        for (int kb = 0; kb < 6; kb++) {
            #pragma unroll
            for (int rt = 0; rt < 4; rt++) {
                s16x8 af = *(const s16x8*)(Ar + ((rt * 6 + kb) * 64 + L) * 8);
                #pragma unroll
                for (int g = 0; g < 4; g++)
                    acc[rt][g] = __builtin_amdgcn_mfma_f32_16x16x32_bf16(
                        af, Bf[g][kb], acc[rt][g], 0, 0, 0);
            }
        }

        // ---- activations + h/c reg update + unconditional h-write to Aw ----
        unsigned mbits = 0;
        #pragma unroll
        for (int rt = 0; rt < 4; rt++)
            #pragma unroll
            for (int r = 0; r < 4; r++) {
                int m = rt * 16 + quad * 4 + r;
                int mval = msk_s[t & 1][m];
                float gi = sigf(acc[rt][0][r]);
                float gf = sigf(acc[rt][1][r]);
                float gg = tanhf_fast(acc[rt][2][r]);
                float go = sigf(acc[rt][3][r]);
                float cn = fmaf(gf, c[rt][r], gi * gg);
                float hv = go * tanhf_fast(cn);
                unsigned short hb = f2bf_hw(hv);
                if (mval) { c[rt][r] = cn; hr[rt][r] = hb; mbits |= 1u << (rt * 4 + r); }
                Aw[((rt * 6 + kb_u) * 64 + fl + r) * 8 + j_u] = hr[rt][r];
            }

        // ---- emb(t+1) + mask(t+1) -> Aw (consume prefetched values) ----
        if (t + 1 < T_STEPS) {
            s16x8 ev;
            #pragma unroll
            for (int j = 0; j < 8; j++) {
                int e = eb * 8 + j;
                float v = fmaf(xv.x, We_s[e], fmaf(xv.y, We_s[D_EMB + e], be_s[e]));
                ev[j] = (short)f2bf_hw(fmaxf(v, 0.0f));
            }
            *(s16x8*)(Aw + idx_e) = ev;
            if (tid < MT) msk_s[(t + 1) & 1][tid] = lm;
        }

        __syncthreads();   // THE barrier: Aw (h+emb), msk ready for t+1

        // ---- coalesced store of out(t-1) from staging (f32x4, 80 lanes) ----
        if (t > 0 && tid < MT * D_OUT / 4)
            ((f32x4*)(out + ((size_t)(t - 1) * NN + n_base) * D_OUT))[tid] =
                ((const f32x4*)st_out[(t - 1) & 1])[tid];

        // ---- out-proj(t): waves 0..3, reads Aw h-rows (post-barrier) ----
        if (wave < 4) {
            f32x4 ao = (f32x4){0.0f, 0.0f, 0.0f, 0.0f};
            #pragma unroll
            for (int kb2 = 0; kb2 < 4; kb2++) {
                s16x8 af = *(const s16x8*)(Aw + ((wave * 6 + 2 + kb2) * 64 + L) * 8);
                ao = __builtin_amdgcn_mfma_f32_16x16x32_bf16(af, WoF[kb2], ao, 0, 0, 0);
            }
            if (l15 < D_OUT) {
                #pragma unroll
                for (int r = 0; r < 4; r++) {
                    int node = wave * 16 + quad * 4 + r;
                    int mv = (mbits >> (wave * 4 + r)) & 1u;
                    st_out[t & 1][node * D_OUT + l15] = mv ? (ao[r] + bo) : 0.0f;
                }
            }
        }
    }

    __syncthreads();   // st_out(19) visible
    if (tid < MT * D_OUT / 4)
        ((f32x4*)(out + ((size_t)(T_STEPS - 1) * NN + n_base) * D_OUT))[tid] =
            ((const f32x4*)st_out[(T_STEPS - 1) & 1])[tid];

    // ---- epilogue: h_fin from regs (bf16), c_fin exact fp32 from regs ----
    #pragma unroll
    for (int rt = 0; rt < 4; rt++)
        #pragma unroll
        for (int r = 0; r < 4; r++) {
            int m = rt * 16 + quad * 4 + r;
            out[OFF_H + (size_t)(n_base + m) * D_H + u_lane] = bf2f(hr[rt][r]);
            out[OFF_C + (size_t)(n_base + m) * D_H + u_lane] = c[rt][r];
        }
}

extern "C" void kernel_launch(void* const* d_in, const int* in_sizes, int n_in,
                              void* d_out, int out_size, void* d_ws, size_t ws_size,
                              hipStream_t stream) {
    const float* nodes   = (const float*)d_in[0];
    const int*   mask    = (const int*)  d_in[1];
    const float* h0      = (const float*)d_in[2];
    const float* c0      = (const float*)d_in[3];
    const float* W_embed = (const float*)d_in[4];
    const float* b_embed = (const float*)d_in[5];
    const float* W_ih    = (const float*)d_in[6];
    const float* b_ih    = (const float*)d_in[7];
    const float* W_hh    = (const float*)d_in[8];
    const float* b_hh    = (const float*)d_in[9];
    const float* W_out   = (const float*)d_in[10];
    const float* b_out   = (const float*)d_in[11];
    float* out = (float*)d_out;

    unsigned short* Wp    = (unsigned short*)d_ws;
    unsigned short* WoutF = Wp + WP_ELEMS;
    float*          b_sum = (float*)(WoutF + WOUT_ELEMS);

    prepack_kernel<<<(WP_ELEMS + WOUT_ELEMS + 255) / 256, 256, 0, stream>>>(
        W_ih, b_ih, W_hh, b_hh, W_out, Wp, WoutF, b_sum);

    vlstm_kernel<<<GRID, BLOCK, 0, stream>>>(
        nodes, mask, h0, c0, W_embed, b_embed, b_out, Wp, WoutF, b_sum, out);
}

// Round 2
// 282.943 us; speedup vs baseline: 1.2038x; 1.2038x over previous
//
#include <hip/hip_runtime.h>
#include <cstddef>

// ============================================================================
// VLSTM via bf16 MFMA, R6: write-path fix + prescaled activations + ballot mask.
//  - R5 post-mortem: scattered per-reg h_fin epilogue caused 64B partial-line
//    RMW (+73MB WRITE, +6MB FETCH). Reverted to coalesced LDS-read epilogue;
//    c_fin (scattered since R4) now staged via LDS (stride-129) too.
//  - Prepack folds log2e scales into gate weights/bias: i,f,o x(-log2e),
//    g x(2*log2e); c carried as c2=2c. Activations: rcp(1+exp2(acc)) directly,
//    tanh via 1 fma. ~80 fewer VALU ops/thread/step.
//  - Mask: wave0 __ballot -> uint64 in LDS (1 ds_read_b64/thread/step instead
//    of 16 ds_read_b32). out(t-1) store moved to waves 4-7 (0-3 do out-proj).
//  - Structure from R5 kept: A dbuf, 1 barrier/step, reg-resident weights,
//    h in regs written unconditionally, x/mask prefetch at loop top.
// ============================================================================

typedef __attribute__((ext_vector_type(8))) short  s16x8;   // 8 x bf16
typedef __attribute__((ext_vector_type(4))) float  f32x4;

namespace {
constexpr int T_STEPS = 20;
constexpr int NN      = 32768;
constexpr int D_EMB   = 64;
constexpr int D_H     = 128;
constexpr int D_OUT   = 5;
constexpr int G4      = 512;
constexpr int MT      = 64;
constexpr int BLOCK   = 512;
constexpr int GRID    = NN / MT;
constexpr int WP_ELEMS   = 8 * 4 * 6 * 64 * 8;
constexpr int WOUT_ELEMS = 4 * 64 * 8;
constexpr int A_ELEMS    = 24 * 64 * 8;
constexpr float LOG2E = 1.4426950408889634f;
constexpr size_t OFF_H = (size_t)T_STEPS * NN * D_OUT;
constexpr size_t OFF_C = OFF_H + (size_t)NN * D_H;
}

__device__ __forceinline__ unsigned short f2bf(float x) {
    unsigned u = __float_as_uint(x);
    u = (u + 0x7FFFu + ((u >> 16) & 1u)) >> 16;     // RNE
    return (unsigned short)u;
}
__device__ __forceinline__ unsigned short f2bf_hw(float x) {
    __bf16 b = (__bf16)x;                            // RNE, hw cvt on gfx950
    union { __bf16 b; unsigned short u; } cv;
    cv.b = b;
    return cv.u;
}
__device__ __forceinline__ float bf2f(unsigned short h) {
    return __uint_as_float(((unsigned)h) << 16);
}
__device__ __forceinline__ float exp2f_fast(float x) {
#if __has_builtin(__builtin_amdgcn_exp2f)
    return __builtin_amdgcn_exp2f(x);
#else
    return __expf(x * 0.6931471805599453f);          // exp(x*ln2) == 2^x
#endif
}
// sigmoid of original x, given a = -x*log2e (prescaled)
__device__ __forceinline__ float sig_pre(float a) {
    return __builtin_amdgcn_rcpf(1.0f + exp2f_fast(a));
}

// ----------------------------------------------------------------------------
__global__ void prepack_kernel(const float* __restrict__ W_ih,
                               const float* __restrict__ b_ih,
                               const float* __restrict__ W_hh,
                               const float* __restrict__ b_hh,
                               const float* __restrict__ W_out,
                               unsigned short* __restrict__ Wp,
                               unsigned short* __restrict__ WoutF,
                               float* __restrict__ b_sum) {
    int idx = blockIdx.x * blockDim.x + threadIdx.x;
    if (idx < WP_ELEMS) {
        int j    = idx & 7;
        int L    = (idx >> 3) & 63;
        int rest = idx >> 9;
        int kb   = rest % 6;
        int gw   = rest / 6;
        int g    = gw & 3, w = gw >> 2;
        int k    = kb * 32 + (L >> 4) * 8 + j;
        int col  = g * D_H + w * 16 + (L & 15);
        float v  = (k < D_EMB) ? W_ih[k * G4 + col] : W_hh[(k - D_EMB) * G4 + col];
        float s  = (g == 2) ? (2.0f * LOG2E) : (-LOG2E);   // i,f,o: -log2e; g: 2log2e
        Wp[idx] = f2bf(v * s);
    } else if (idx < WP_ELEMS + WOUT_ELEMS) {
        int i2 = idx - WP_ELEMS;
        int j = i2 & 7, L = (i2 >> 3) & 63, kb2 = i2 >> 9;
        int k = kb2 * 32 + (L >> 4) * 8 + j;
        int n = L & 15;
        WoutF[i2] = (n < D_OUT) ? f2bf(W_out[k * D_OUT + n]) : (unsigned short)0;
    }
    if (idx < G4) {
        int g = idx / D_H;
        float s = (g == 2) ? (2.0f * LOG2E) : (-LOG2E);
        b_sum[idx] = (b_ih[idx] + b_hh[idx]) * s;
    }
}

// ----------------------------------------------------------------------------
__global__ __launch_bounds__(BLOCK, 2) void vlstm_kernel(
    const float* __restrict__ nodes,   // [T][N][2]
    const int*   __restrict__ mask,    // [T][N]
    const float* __restrict__ h0,      // [N][128]
    const float* __restrict__ c0,      // [N][128]
    const float* __restrict__ W_embed, // [2][64]
    const float* __restrict__ b_embed, // [64]
    const float* __restrict__ b_out,   // [5]
    const unsigned short* __restrict__ Wp,
    const unsigned short* __restrict__ WoutF,
    const float* __restrict__ b_sum,
    float* __restrict__ out)
{
    __shared__ __align__(16) unsigned short A[2][A_ELEMS];     // 48 KB dbuf
    __shared__ __align__(16) float st_out[2][MT * D_OUT];      // 2.5 KB dbuf
    __shared__ float We_s[2 * D_EMB];
    __shared__ float be_s[D_EMB];
    __shared__ unsigned long long msk64[2];

    const int tid  = threadIdx.x;
    const int wave = tid >> 6;
    const int L    = tid & 63;
    const int quad = L >> 4;
    const int l15  = L & 15;
    const int n_base = blockIdx.x * MT;

    // ---- weights -> registers, once ----
    const unsigned short* wbase = Wp + (size_t)wave * (4 * 6 * 64 * 8);
    s16x8 Bf[4][6];
    #pragma unroll
    for (int g = 0; g < 4; g++)
        #pragma unroll
        for (int kb = 0; kb < 6; kb++)
            Bf[g][kb] = *(const s16x8*)(wbase + ((g * 6 + kb) * 64 + L) * 8);
    s16x8 WoF[4];
    #pragma unroll
    for (int kb2 = 0; kb2 < 4; kb2++)
        WoF[kb2] = *(const s16x8*)(WoutF + ((kb2 * 64) + L) * 8);

    const int u_lane = wave * 16 + l15;
    float bias[4];
    #pragma unroll
    for (int g = 0; g < 4; g++) bias[g] = b_sum[g * D_H + wave * 16 + l15];
    const float bo = (l15 < D_OUT) ? b_out[l15] : 0.0f;

    // per-thread A-write geometry (h rows)
    const int kb_u = 2 + (u_lane >> 5);
    const int fl   = ((u_lane >> 3) & 3) * 16 + quad * 4;
    const int j_u  = u_lane & 7;

    // ---- one-time LDS staging ----
    for (int i = tid; i < 3 * D_EMB; i += BLOCK) {
        if (i < 2 * D_EMB) We_s[i] = W_embed[i];
        else               be_s[i - 2 * D_EMB] = b_embed[i - 2 * D_EMB];
    }

    // ---- h, c -> registers (c as c2=2c); h -> A[0] h-rows ----
    float          c2[4][4];
    unsigned short hr[4][4];
    #pragma unroll
    for (int rt = 0; rt < 4; rt++)
        #pragma unroll
        for (int r = 0; r < 4; r++) {
            int m = rt * 16 + quad * 4 + r;
            c2[rt][r] = 2.0f * c0[(size_t)(n_base + m) * D_H + u_lane];
            hr[rt][r] = f2bf_hw(h0[(size_t)(n_base + m) * D_H + u_lane]);
            A[0][((rt * 6 + kb_u) * 64 + fl + r) * 8 + j_u] = hr[rt][r];
        }

    // ---- emb(0) + mask(0) -> A[0] ----
    const int node_e = tid >> 3;
    const int eb     = tid & 7;
    const int idx_e  = (((node_e >> 4) * 6 + (eb >> 2)) * 64 + (eb & 3) * 16 + (node_e & 15)) * 8;
    {
        const float2* xp = (const float2*)(nodes + ((size_t)0 * NN + n_base + node_e) * 2);
        float2 x = *xp;
        s16x8 ev;
        #pragma unroll
        for (int j = 0; j < 8; j++) {
            int e = eb * 8 + j;
            float v = fmaf(x.x, We_s[e], fmaf(x.y, We_s[D_EMB + e], be_s[e]));
            ev[j] = (short)f2bf_hw(fmaxf(v, 0.0f));
        }
        *(s16x8*)(&A[0][idx_e]) = ev;
        if (wave == 0) {
            int lm0 = mask[n_base + L];
            unsigned long long bm0 = __ballot(lm0 != 0);
            if (L == 0) msk64[0] = bm0;
        }
    }
    __syncthreads();   // prologue barrier: A[0], msk64[0] ready

    for (int t = 0; t < T_STEPS; t++) {
        unsigned short* __restrict__ Ar = A[t & 1];
        unsigned short* __restrict__ Aw = A[(t + 1) & 1];

        // ---- prefetch x(t+1), mask(t+1) (issue early, consume late) ----
        float2 xv = make_float2(0.0f, 0.0f);
        int    lm = 0;
        if (t + 1 < T_STEPS) {
            xv = *(const float2*)(nodes + ((size_t)(t + 1) * NN + n_base + node_e) * 2);
            if (wave == 0) lm = mask[(size_t)(t + 1) * NN + n_base + L];
        }
        const unsigned long long M = msk64[t & 1];   // 1 ds_read_b64, broadcast

        // ---- gate GEMM from Ar: 24 ds_read_b128 + 96 MFMA/wave ----
        f32x4 acc[4][4];
        #pragma unroll
        for (int rt = 0; rt < 4; rt++)
            #pragma unroll
            for (int g = 0; g < 4; g++)
                acc[rt][g] = (f32x4){bias[g], bias[g], bias[g], bias[g]};
        #pragma unroll
        for (int kb = 0; kb < 6; kb++) {
            #pragma unroll
            for (int rt = 0; rt < 4; rt++) {
                s16x8 af = *(const s16x8*)(Ar + ((rt * 6 + kb) * 64 + L) * 8);
                #pragma unroll
                for (int g = 0; g < 4; g++)
                    acc[rt][g] = __builtin_amdgcn_mfma_f32_16x16x32_bf16(
                        af, Bf[g][kb], acc[rt][g], 0, 0, 0);
            }
        }

        // ---- activations (prescaled) + h/c2 update + h-write to Aw ----
        #pragma unroll
        for (int rt = 0; rt < 4; rt++) {
            unsigned nib = (unsigned)(M >> (rt * 16 + quad * 4)) & 0xFu;
            #pragma unroll
            for (int r = 0; r < 4; r++) {
                float gi = sig_pre(acc[rt][0][r]);
                float gf = sig_pre(acc[rt][1][r]);
                float rg = sig_pre(acc[rt][2][r]);               // rcp(1+e^{2g})
                float go = sig_pre(acc[rt][3][r]);
                float gg2 = fmaf(-4.0f, rg, 2.0f);               // 2*tanh(g)
                float cn2 = fmaf(gf, c2[rt][r], gi * gg2);       // 2*c_new
                float rr = __builtin_amdgcn_rcpf(1.0f + exp2f_fast(cn2 * LOG2E));
                float hv = go * fmaf(-2.0f, rr, 1.0f);           // o*tanh(c_new)
                unsigned short hb = f2bf_hw(hv);
                if ((nib >> r) & 1u) { c2[rt][r] = cn2; hr[rt][r] = hb; }
                Aw[((rt * 6 + kb_u) * 64 + fl + r) * 8 + j_u] = hr[rt][r];
            }
        }

        // ---- emb(t+1) + mask(t+1) -> Aw (consume prefetched values) ----
        if (t + 1 < T_STEPS) {
            s16x8 ev;
            #pragma unroll
            for (int j = 0; j < 8; j++) {
                int e = eb * 8 + j;
                float v = fmaf(xv.x, We_s[e], fmaf(xv.y, We_s[D_EMB + e], be_s[e]));
                ev[j] = (short)f2bf_hw(fmaxf(v, 0.0f));
            }
            *(s16x8*)(Aw + idx_e) = ev;
            if (wave == 0) {
                unsigned long long bm = __ballot(lm != 0);
                if (L == 0) msk64[(t + 1) & 1] = bm;
            }
        }

        __syncthreads();   // THE barrier: Aw (h+emb), msk ready for t+1

        // ---- coalesced store of out(t-1): waves 4-7 (0-3 do out-proj) ----
        if (t > 0 && wave >= 4) {
            int j = tid - 256;
            if (j < MT * D_OUT / 4)
                ((f32x4*)(out + ((size_t)(t - 1) * NN + n_base) * D_OUT))[j] =
                    ((const f32x4*)st_out[(t - 1) & 1])[j];
        }

        // ---- out-proj(t): waves 0..3, reads Aw h-rows (post-barrier) ----
        if (wave < 4) {
            f32x4 ao = (f32x4){0.0f, 0.0f, 0.0f, 0.0f};
            #pragma unroll
            for (int kb2 = 0; kb2 < 4; kb2++) {
                s16x8 af = *(const s16x8*)(Aw + ((wave * 6 + 2 + kb2) * 64 + L) * 8);
                ao = __builtin_amdgcn_mfma_f32_16x16x32_bf16(af, WoF[kb2], ao, 0, 0, 0);
            }
            if (l15 < D_OUT) {
                unsigned nib_o = (unsigned)(M >> (wave * 16 + quad * 4)) & 0xFu;
                #pragma unroll
                for (int r = 0; r < 4; r++) {
                    int node = wave * 16 + quad * 4 + r;
                    st_out[t & 1][node * D_OUT + l15] =
                        ((nib_o >> r) & 1u) ? (ao[r] + bo) : 0.0f;
                }
            }
        }
    }

    __syncthreads();   // st_out(19) + A[0] final h visible
    if (tid < MT * D_OUT / 4)
        ((f32x4*)(out + ((size_t)(T_STEPS - 1) * NN + n_base) * D_OUT))[tid] =
            ((const f32x4*)st_out[(T_STEPS - 1) & 1])[tid];

    // ---- h_fin: coalesced from A[0] (final merged h, bf16) ----
    for (int i = tid; i < MT * D_H; i += BLOCK) {
        int node = i >> 7, u = i & 127;
        int k = D_EMB + u;
        int idx = (((node >> 4) * 6 + (k >> 5)) * 64 + ((k >> 3) & 3) * 16 + (node & 15)) * 8 + (k & 7);
        out[OFF_H + (size_t)(n_base + node) * D_H + u] = bf2f(A[0][idx]);
    }

    // ---- c_fin: stage via LDS (stride 129, conflict-free), coalesced copy ----
    __syncthreads();                    // h_fin reads of A done
    float* cs = (float*)A;              // reuse 48 KB; need 64*129*4 = 33 KB
    #pragma unroll
    for (int rt = 0; rt < 4; rt++)
        #pragma unroll
        for (int r = 0; r < 4; r++) {
            int m = rt * 16 + quad * 4 + r;
            cs[m * 129 + u_lane] = 0.5f * c2[rt][r];   // exact halving
        }
    __syncthreads();
    for (int i = tid; i < MT * D_H; i += BLOCK) {
        int node = i >> 7, u = i & 127;
        out[OFF_C + (size_t)(n_base + node) * D_H + u] = cs[node * 129 + u];
    }
}

extern "C" void kernel_launch(void* const* d_in, const int* in_sizes, int n_in,
                              void* d_out, int out_size, void* d_ws, size_t ws_size,
                              hipStream_t stream) {
    const float* nodes   = (const float*)d_in[0];
    const int*   mask    = (const int*)  d_in[1];
    const float* h0      = (const float*)d_in[2];
    const float* c0      = (const float*)d_in[3];
    const float* W_embed = (const float*)d_in[4];
    const float* b_embed = (const float*)d_in[5];
    const float* W_ih    = (const float*)d_in[6];
    const float* b_ih    = (const float*)d_in[7];
    const float* W_hh    = (const float*)d_in[8];
    const float* b_hh    = (const float*)d_in[9];
    const float* W_out   = (const float*)d_in[10];
    const float* b_out   = (const float*)d_in[11];
    float* out = (float*)d_out;

    unsigned short* Wp    = (unsigned short*)d_ws;
    unsigned short* WoutF = Wp + WP_ELEMS;
    float*          b_sum = (float*)(WoutF + WOUT_ELEMS);

    prepack_kernel<<<(WP_ELEMS + WOUT_ELEMS + 255) / 256, 256, 0, stream>>>(
        W_ih, b_ih, W_hh, b_hh, W_out, Wp, WoutF, b_sum);

    vlstm_kernel<<<GRID, BLOCK, 0, stream>>>(
        nodes, mask, h0, c0, W_embed, b_embed, b_out, Wp, WoutF, b_sum, out);
}

// Round 3
// 274.266 us; speedup vs baseline: 1.2419x; 1.0316x over previous
//
#include <hip/hip_runtime.h>
#include <cstddef>

// ============================================================================
// VLSTM via bf16 MFMA, R7: row-tile-interleaved GEMM/ACT + bias-as-MFMA-C.
//  - R6 analysis: 12,240 cyc/step; MFMA needs 3.7k (27%), VALU 6.1k (50%),
//    sum 80% => phases are serialized (2 lockstep waves/SIMD, no cross-wave
//    overlap). ACT(rt) only needs acc[rt][*], so interleave:
//    G0 G1 G2 A0 G3 A1 emb A2 A3 -> trans/VALU of ACT(rt) hides under
//    MFMAs of GEMM(rt+2) within each wave.
//  - acc init eliminated: biasv[g] (f32x4, persistent) is the C operand of
//    the kb=0 MFMA (-64 accvgpr_write/wave/step).
//  - c carried as cL = 2c*log2e: tanh(c_new) arg needs no mul; de-scale once
//    in the epilogue.
//  - All R6 structure kept: A dbuf 1 barrier/step, reg weights, ballot mask,
//    coalesced LDS-staged outputs/epilogue, prescaled gate weights.
// ============================================================================

typedef __attribute__((ext_vector_type(8))) short  s16x8;   // 8 x bf16
typedef __attribute__((ext_vector_type(4))) float  f32x4;

namespace {
constexpr int T_STEPS = 20;
constexpr int NN      = 32768;
constexpr int D_EMB   = 64;
constexpr int D_H     = 128;
constexpr int D_OUT   = 5;
constexpr int G4      = 512;
constexpr int MT      = 64;
constexpr int BLOCK   = 512;
constexpr int GRID    = NN / MT;
constexpr int WP_ELEMS   = 8 * 4 * 6 * 64 * 8;
constexpr int WOUT_ELEMS = 4 * 64 * 8;
constexpr int A_ELEMS    = 24 * 64 * 8;
constexpr float LOG2E = 1.4426950408889634f;
constexpr float AM4   = -4.0f * LOG2E;          // -5.7707801636
constexpr float AP2   =  2.0f * LOG2E;          //  2.8853900818
constexpr float CINV  = 0.34657359027997264f;   //  1/(2*log2e)
constexpr size_t OFF_H = (size_t)T_STEPS * NN * D_OUT;
constexpr size_t OFF_C = OFF_H + (size_t)NN * D_H;
}

__device__ __forceinline__ unsigned short f2bf(float x) {
    unsigned u = __float_as_uint(x);
    u = (u + 0x7FFFu + ((u >> 16) & 1u)) >> 16;     // RNE
    return (unsigned short)u;
}
__device__ __forceinline__ unsigned short f2bf_hw(float x) {
    __bf16 b = (__bf16)x;                            // RNE, hw cvt on gfx950
    union { __bf16 b; unsigned short u; } cv;
    cv.b = b;
    return cv.u;
}
__device__ __forceinline__ float bf2f(unsigned short h) {
    return __uint_as_float(((unsigned)h) << 16);
}
__device__ __forceinline__ float exp2f_fast(float x) {
#if __has_builtin(__builtin_amdgcn_exp2f)
    return __builtin_amdgcn_exp2f(x);
#else
    return __expf(x * 0.6931471805599453f);
#endif
}
// sigmoid of original x, given a = -x*log2e (prescaled)
__device__ __forceinline__ float sig_pre(float a) {
    return __builtin_amdgcn_rcpf(1.0f + exp2f_fast(a));
}

// ----------------------------------------------------------------------------
__global__ void prepack_kernel(const float* __restrict__ W_ih,
                               const float* __restrict__ b_ih,
                               const float* __restrict__ W_hh,
                               const float* __restrict__ b_hh,
                               const float* __restrict__ W_out,
                               unsigned short* __restrict__ Wp,
                               unsigned short* __restrict__ WoutF,
                               float* __restrict__ b_sum) {
    int idx = blockIdx.x * blockDim.x + threadIdx.x;
    if (idx < WP_ELEMS) {
        int j    = idx & 7;
        int L    = (idx >> 3) & 63;
        int rest = idx >> 9;
        int kb   = rest % 6;
        int gw   = rest / 6;
        int g    = gw & 3, w = gw >> 2;
        int k    = kb * 32 + (L >> 4) * 8 + j;
        int col  = g * D_H + w * 16 + (L & 15);
        float v  = (k < D_EMB) ? W_ih[k * G4 + col] : W_hh[(k - D_EMB) * G4 + col];
        float s  = (g == 2) ? (2.0f * LOG2E) : (-LOG2E);   // i,f,o: -log2e; g: 2log2e
        Wp[idx] = f2bf(v * s);
    } else if (idx < WP_ELEMS + WOUT_ELEMS) {
        int i2 = idx - WP_ELEMS;
        int j = i2 & 7, L = (i2 >> 3) & 63, kb2 = i2 >> 9;
        int k = kb2 * 32 + (L >> 4) * 8 + j;
        int n = L & 15;
        WoutF[i2] = (n < D_OUT) ? f2bf(W_out[k * D_OUT + n]) : (unsigned short)0;
    }
    if (idx < G4) {
        int g = idx / D_H;
        float s = (g == 2) ? (2.0f * LOG2E) : (-LOG2E);
        b_sum[idx] = (b_ih[idx] + b_hh[idx]) * s;
    }
}

// ----------------------------------------------------------------------------
__global__ __launch_bounds__(BLOCK, 2) void vlstm_kernel(
    const float* __restrict__ nodes,   // [T][N][2]
    const int*   __restrict__ mask,    // [T][N]
    const float* __restrict__ h0,      // [N][128]
    const float* __restrict__ c0,      // [N][128]
    const float* __restrict__ W_embed, // [2][64]
    const float* __restrict__ b_embed, // [64]
    const float* __restrict__ b_out,   // [5]
    const unsigned short* __restrict__ Wp,
    const unsigned short* __restrict__ WoutF,
    const float* __restrict__ b_sum,
    float* __restrict__ out)
{
    __shared__ __align__(16) unsigned short A[2][A_ELEMS];     // 48 KB dbuf
    __shared__ __align__(16) float st_out[2][MT * D_OUT];      // 2.5 KB dbuf
    __shared__ float We_s[2 * D_EMB];
    __shared__ float be_s[D_EMB];
    __shared__ unsigned long long msk64[2];

    const int tid  = threadIdx.x;
    const int wave = tid >> 6;
    const int L    = tid & 63;
    const int quad = L >> 4;
    const int l15  = L & 15;
    const int n_base = blockIdx.x * MT;

    // ---- weights -> registers, once ----
    const unsigned short* wbase = Wp + (size_t)wave * (4 * 6 * 64 * 8);
    s16x8 Bf[4][6];
    #pragma unroll
    for (int g = 0; g < 4; g++)
        #pragma unroll
        for (int kb = 0; kb < 6; kb++)
            Bf[g][kb] = *(const s16x8*)(wbase + ((g * 6 + kb) * 64 + L) * 8);
    s16x8 WoF[4];
    #pragma unroll
    for (int kb2 = 0; kb2 < 4; kb2++)
        WoF[kb2] = *(const s16x8*)(WoutF + ((kb2 * 64) + L) * 8);

    const int u_lane = wave * 16 + l15;
    f32x4 biasv[4];
    #pragma unroll
    for (int g = 0; g < 4; g++) {
        float b = b_sum[g * D_H + wave * 16 + l15];
        biasv[g] = (f32x4){b, b, b, b};
    }
    const float bo = (l15 < D_OUT) ? b_out[l15] : 0.0f;

    // per-thread A-write geometry (h rows)
    const int kb_u = 2 + (u_lane >> 5);
    const int fl   = ((u_lane >> 3) & 3) * 16 + quad * 4;
    const int j_u  = u_lane & 7;

    // ---- one-time LDS staging ----
    for (int i = tid; i < 3 * D_EMB; i += BLOCK) {
        if (i < 2 * D_EMB) We_s[i] = W_embed[i];
        else               be_s[i - 2 * D_EMB] = b_embed[i - 2 * D_EMB];
    }

    // ---- h, c -> registers (c as cL = 2c*log2e); h -> A[0] h-rows ----
    float          cL[4][4];
    unsigned short hr[4][4];
    #pragma unroll
    for (int rt = 0; rt < 4; rt++)
        #pragma unroll
        for (int r = 0; r < 4; r++) {
            int m = rt * 16 + quad * 4 + r;
            cL[rt][r] = AP2 * c0[(size_t)(n_base + m) * D_H + u_lane];
            hr[rt][r] = f2bf_hw(h0[(size_t)(n_base + m) * D_H + u_lane]);
            A[0][((rt * 6 + kb_u) * 64 + fl + r) * 8 + j_u] = hr[rt][r];
        }

    // ---- emb(0) + mask(0) -> A[0] ----
    const int node_e = tid >> 3;
    const int eb     = tid & 7;
    const int idx_e  = (((node_e >> 4) * 6 + (eb >> 2)) * 64 + (eb & 3) * 16 + (node_e & 15)) * 8;
    {
        const float2* xp = (const float2*)(nodes + ((size_t)0 * NN + n_base + node_e) * 2);
        float2 x = *xp;
        s16x8 ev;
        #pragma unroll
        for (int j = 0; j < 8; j++) {
            int e = eb * 8 + j;
            float v = fmaf(x.x, We_s[e], fmaf(x.y, We_s[D_EMB + e], be_s[e]));
            ev[j] = (short)f2bf_hw(fmaxf(v, 0.0f));
        }
        *(s16x8*)(&A[0][idx_e]) = ev;
        if (wave == 0) {
            int lm0 = mask[n_base + L];
            unsigned long long bm0 = __ballot(lm0 != 0);
            if (L == 0) msk64[0] = bm0;
        }
    }
    __syncthreads();   // prologue barrier: A[0], msk64[0] ready

// GEMM of one row-tile: kb=0 MFMA uses biasv as C (no acc init), kb=1..5 chain
#define GEMM_RT(rt) do {                                                       \
    {   s16x8 af0 = *(const s16x8*)(Ar + (((rt) * 6 + 0) * 64 + L) * 8);       \
        _Pragma("unroll")                                                      \
        for (int g = 0; g < 4; g++)                                            \
            acc[rt][g] = __builtin_amdgcn_mfma_f32_16x16x32_bf16(              \
                af0, Bf[g][0], biasv[g], 0, 0, 0); }                           \
    _Pragma("unroll")                                                          \
    for (int kb = 1; kb < 6; kb++) {                                           \
        s16x8 af = *(const s16x8*)(Ar + (((rt) * 6 + kb) * 64 + L) * 8);       \
        _Pragma("unroll")                                                      \
        for (int g = 0; g < 4; g++)                                            \
            acc[rt][g] = __builtin_amdgcn_mfma_f32_16x16x32_bf16(              \
                af, Bf[g][kb], acc[rt][g], 0, 0, 0); }                         \
} while (0)

// Activations + h/c update + h-write for one row-tile
#define ACT_RT(rt) do {                                                        \
    unsigned nib = (unsigned)(M >> ((rt) * 16 + quad * 4)) & 0xFu;             \
    _Pragma("unroll")                                                          \
    for (int r = 0; r < 4; r++) {                                              \
        float gi = sig_pre(acc[rt][0][r]);                                     \
        float gf = sig_pre(acc[rt][1][r]);                                     \
        float rg = sig_pre(acc[rt][2][r]);                                     \
        float go = sig_pre(acc[rt][3][r]);                                     \
        float ggL = fmaf(AM4, rg, AP2);            /* 2*log2e*tanh(g) */       \
        float cnL = fmaf(gf, cL[rt][r], gi * ggL); /* 2*log2e*c_new   */       \
        float rr  = __builtin_amdgcn_rcpf(1.0f + exp2f_fast(cnL));             \
        float hv  = go * fmaf(-2.0f, rr, 1.0f);    /* o*tanh(c_new)   */       \
        unsigned short hb = f2bf_hw(hv);                                       \
        if ((nib >> r) & 1u) { cL[rt][r] = cnL; hr[rt][r] = hb; }              \
        Aw[(((rt) * 6 + kb_u) * 64 + fl + r) * 8 + j_u] = hr[rt][r];           \
    }                                                                          \
} while (0)

    for (int t = 0; t < T_STEPS; t++) {
        unsigned short* __restrict__ Ar = A[t & 1];
        unsigned short* __restrict__ Aw = A[(t + 1) & 1];

        // ---- prefetch x(t+1), mask(t+1) (issue early, consume late) ----
        float2 xv = make_float2(0.0f, 0.0f);
        int    lm = 0;
        if (t + 1 < T_STEPS) {
            xv = *(const float2*)(nodes + ((size_t)(t + 1) * NN + n_base + node_e) * 2);
            if (wave == 0) lm = mask[(size_t)(t + 1) * NN + n_base + L];
        }
        const unsigned long long M = msk64[t & 1];   // 1 ds_read_b64, broadcast

        // ---- interleaved GEMM/ACT: ACT(rt) hides under GEMM(rt+2) ----
        f32x4 acc[4][4];
        GEMM_RT(0);
        GEMM_RT(1);
        GEMM_RT(2);
        ACT_RT(0);
        GEMM_RT(3);
        ACT_RT(1);

        // ---- emb(t+1) + mask(t+1) -> Aw (consume prefetched values) ----
        if (t + 1 < T_STEPS) {
            s16x8 ev;
            #pragma unroll
            for (int j = 0; j < 8; j++) {
                int e = eb * 8 + j;
                float v = fmaf(xv.x, We_s[e], fmaf(xv.y, We_s[D_EMB + e], be_s[e]));
                ev[j] = (short)f2bf_hw(fmaxf(v, 0.0f));
            }
            *(s16x8*)(Aw + idx_e) = ev;
            if (wave == 0) {
                unsigned long long bm = __ballot(lm != 0);
                if (L == 0) msk64[(t + 1) & 1] = bm;
            }
        }

        ACT_RT(2);
        ACT_RT(3);

        __syncthreads();   // THE barrier: Aw (h+emb), msk ready for t+1

        // ---- coalesced store of out(t-1): waves 4-7 (0-3 do out-proj) ----
        if (t > 0 && wave >= 4) {
            int j = tid - 256;
            if (j < MT * D_OUT / 4)
                ((f32x4*)(out + ((size_t)(t - 1) * NN + n_base) * D_OUT))[j] =
                    ((const f32x4*)st_out[(t - 1) & 1])[j];
        }

        // ---- out-proj(t): waves 0..3, reads Aw h-rows (post-barrier) ----
        if (wave < 4) {
            f32x4 ao = (f32x4){0.0f, 0.0f, 0.0f, 0.0f};
            #pragma unroll
            for (int kb2 = 0; kb2 < 4; kb2++) {
                s16x8 af = *(const s16x8*)(Aw + ((wave * 6 + 2 + kb2) * 64 + L) * 8);
                ao = __builtin_amdgcn_mfma_f32_16x16x32_bf16(af, WoF[kb2], ao, 0, 0, 0);
            }
            if (l15 < D_OUT) {
                unsigned nib_o = (unsigned)(M >> (wave * 16 + quad * 4)) & 0xFu;
                #pragma unroll
                for (int r = 0; r < 4; r++) {
                    int node = wave * 16 + quad * 4 + r;
                    st_out[t & 1][node * D_OUT + l15] =
                        ((nib_o >> r) & 1u) ? (ao[r] + bo) : 0.0f;
                }
            }
        }
    }
#undef GEMM_RT
#undef ACT_RT

    __syncthreads();   // st_out(19) + A[0] final h visible
    if (tid < MT * D_OUT / 4)
        ((f32x4*)(out + ((size_t)(T_STEPS - 1) * NN + n_base) * D_OUT))[tid] =
            ((const f32x4*)st_out[(T_STEPS - 1) & 1])[tid];

    // ---- h_fin: coalesced from A[0] (final merged h, bf16) ----
    for (int i = tid; i < MT * D_H; i += BLOCK) {
        int node = i >> 7, u = i & 127;
        int k = D_EMB + u;
        int idx = (((node >> 4) * 6 + (k >> 5)) * 64 + ((k >> 3) & 3) * 16 + (node & 15)) * 8 + (k & 7);
        out[OFF_H + (size_t)(n_base + node) * D_H + u] = bf2f(A[0][idx]);
    }

    // ---- c_fin: stage via LDS (stride 129, conflict-free), coalesced copy ----
    __syncthreads();                    // h_fin reads of A done
    float* cs = (float*)A;              // reuse 48 KB; need 64*129*4 = 33 KB
    #pragma unroll
    for (int rt = 0; rt < 4; rt++)
        #pragma unroll
        for (int r = 0; r < 4; r++) {
            int m = rt * 16 + quad * 4 + r;
            cs[m * 129 + u_lane] = CINV * cL[rt][r];   // de-scale once
        }
    __syncthreads();
    for (int i = tid; i < MT * D_H; i += BLOCK) {
        int node = i >> 7, u = i & 127;
        out[OFF_C + (size_t)(n_base + node) * D_H + u] = cs[node * 129 + u];
    }
}

extern "C" void kernel_launch(void* const* d_in, const int* in_sizes, int n_in,
                              void* d_out, int out_size, void* d_ws, size_t ws_size,
                              hipStream_t stream) {
    const float* nodes   = (const float*)d_in[0];
    const int*   mask    = (const int*)  d_in[1];
    const float* h0      = (const float*)d_in[2];
    const float* c0      = (const float*)d_in[3];
    const float* W_embed = (const float*)d_in[4];
    const float* b_embed = (const float*)d_in[5];
    const float* W_ih    = (const float*)d_in[6];
    const float* b_ih    = (const float*)d_in[7];
    const float* W_hh    = (const float*)d_in[8];
    const float* b_hh    = (const float*)d_in[9];
    const float* W_out   = (const float*)d_in[10];
    const float* b_out   = (const float*)d_in[11];
    float* out = (float*)d_out;

    unsigned short* Wp    = (unsigned short*)d_ws;
    unsigned short* WoutF = Wp + WP_ELEMS;
    float*          b_sum = (float*)(WoutF + WOUT_ELEMS);

    prepack_kernel<<<(WP_ELEMS + WOUT_ELEMS + 255) / 256, 256, 0, stream>>>(
        W_ih, b_ih, W_hh, b_hh, W_out, Wp, WoutF, b_sum);

    vlstm_kernel<<<GRID, BLOCK, 0, stream>>>(
        nodes, mask, h0, c0, W_embed, b_embed, b_out, Wp, WoutF, b_sum, out);
}